// Round 12
// baseline (343.981 us; speedup 1.0000x reference)
//
#include <hip/hip_runtime.h>
#include <stdint.h>

#define N_NODES 50000
#define N_EDGES 800000
#define IN_CH 128
#define HID 256
#define N_GRAPHS 64
#define N_CLASSES 10

#define GEMM_WG ((N_NODES + 127) / 128)       // 391 blocks (full-width tiles)
#define NB ((N_NODES + 127) / 128)            // 391 dst buckets (128 nodes each)
#define EPB 4096                              // edges per bin_pass block
#define CAP 4096                              // slots per bucket (mean 2048, 45 sigma)
#define GTILES ((N_NODES + 63) / 64)          // 782 gather node-tiles

typedef unsigned short u16;
typedef __attribute__((ext_vector_type(8))) short short8;
typedef __attribute__((ext_vector_type(4))) float f32x4;

__device__ __forceinline__ float bf2f(uint32_t u) {
    union { uint32_t i; float f; } v; v.i = u << 16; return v.f;
}
__device__ __forceinline__ uint32_t f2bf(float f) {
    union { float f; uint32_t i; } v; v.f = f;
    return (v.i + 0x7FFFu + ((v.i >> 16) & 1u)) >> 16;   // RNE
}

// Blocked feature layout: [node/2][NCH][2][32] u16 — one 128 B L2 line holds
// the same 32-col chunk of a row PAIR, so a per-XCD chunk partition has a
// 3.2 MB working set (fits 4 MB L2) with zero line over-fetch.
__device__ __forceinline__ size_t blk_idx(int node, int col, int nch) {
    return ((size_t)(node >> 1) * nch + (col >> 5)) * 64 + (node & 1) * 32 + (col & 31);
}

// ===========================================================================
// CSR build: bin (fixed-capacity buckets) -> bucket scan -> debin
// ===========================================================================
__global__ void __launch_bounds__(512) bin_pass(const int* __restrict__ src,
                                                const int* __restrict__ dst,
                                                int* __restrict__ gcnt,
                                                uint32_t* __restrict__ tmp)
{
    __shared__ int hist[NB];
    __shared__ int base[NB];
    int t = threadIdx.x;
    for (int i = t; i < NB; i += 512) hist[i] = 0;
    __syncthreads();
    const int e0 = blockIdx.x * EPB;
    int b_[8], s_[8], d_[8];
    #pragma unroll
    for (int k = 0; k < 8; ++k) {
        int e = e0 + k * 512 + t;
        if (e < N_EDGES) {
            int d = dst[e];
            b_[k] = d >> 7;
            d_[k] = d & 127;
            s_[k] = src[e];
            atomicAdd(&hist[b_[k]], 1);
        } else b_[k] = -1;
    }
    __syncthreads();
    for (int i = t; i < NB; i += 512) {
        int c = hist[i];
        base[i] = c ? atomicAdd(&gcnt[i], c) : 0;
        hist[i] = 0;
    }
    __syncthreads();
    #pragma unroll
    for (int k = 0; k < 8; ++k) {
        if (b_[k] >= 0) {
            int r = atomicAdd(&hist[b_[k]], 1);
            int pos = base[b_[k]] + r;
            if (pos < CAP)
                tmp[(size_t)b_[k] * CAP + pos] = ((uint32_t)s_[k] << 7) | (uint32_t)d_[k];
        }
    }
}

__global__ void __launch_bounds__(512) bucket_scan(const int* __restrict__ gcnt,
                                                   int* __restrict__ boff,
                                                   int* __restrict__ row_start)
{
    __shared__ int buf[512];
    int t = threadIdx.x;
    int v = (t < NB) ? gcnt[t] : 0;
    buf[t] = v;
    __syncthreads();
    #pragma unroll
    for (int off = 1; off < 512; off <<= 1) {
        int a = (t >= off) ? buf[t - off] : 0;
        __syncthreads();
        buf[t] += a;
        __syncthreads();
    }
    if (t < NB) boff[t] = buf[t] - v;
    if (t == 0) row_start[N_NODES] = N_EDGES;
}

__global__ void __launch_bounds__(256) debin2(const uint32_t* __restrict__ tmp,
                                              const int* __restrict__ gcnt,
                                              const int* __restrict__ boff,
                                              int* __restrict__ row_start,
                                              int* __restrict__ esrc)
{
    __shared__ int h[128];
    __shared__ int pre[128];
    __shared__ int cur[128];
    const int b = blockIdx.x;
    const int n0 = b * 128;
    const int nn = min(128, N_NODES - n0);
    const int t = threadIdx.x;
    const int cnt = min(gcnt[b], CAP);
    const int bb = boff[b];
    const uint32_t* te = tmp + (size_t)b * CAP;

    if (t < 128) h[t] = 0;
    __syncthreads();
    for (int p = t; p < cnt; p += 256)
        atomicAdd(&h[te[p] & 127u], 1);
    __syncthreads();
    if (t < 128) pre[t] = h[t];
    __syncthreads();
    #pragma unroll
    for (int off = 1; off < 128; off <<= 1) {
        int a = (t >= off && t < 128) ? pre[t - off] : 0;
        __syncthreads();
        if (t < 128) pre[t] += a;
        __syncthreads();
    }
    if (t < nn) {
        int rs = bb + pre[t] - h[t];   // exclusive
        row_start[n0 + t] = rs;
        cur[t] = rs;
    }
    __syncthreads();
    for (int p = t; p < cnt; p += 256) {
        uint32_t v = te[p];
        int pos = atomicAdd(&cur[v & 127u], 1);
        esrc[pos] = (int)(v >> 7);
    }
}

// ===========================================================================
// fused conversions: x -> BLOCKED bf16 + 6 weight transposes
// ===========================================================================
#define XB 3125   // N_NODES*IN_CH/8/256
__global__ void __launch_bounds__(256)
cvt_all(const float* __restrict__ x, u16* __restrict__ xblk,
        const float* __restrict__ W1r, const float* __restrict__ W1n,
        const float* __restrict__ W2r, const float* __restrict__ W2n,
        const float* __restrict__ W3r, const float* __restrict__ W3n,
        u16* __restrict__ o1r, u16* __restrict__ o1n,
        u16* __restrict__ o2r, u16* __restrict__ o2n,
        u16* __restrict__ o3r, u16* __restrict__ o3n)
{
    if (blockIdx.x < XB) {
        int id = blockIdx.x * 256 + threadIdx.x;
        int node = id >> 4;
        int col0 = (id & 15) * 8;
        const float4 a = *reinterpret_cast<const float4*>(x + (size_t)id * 8);
        const float4 b = *reinterpret_cast<const float4*>(x + (size_t)id * 8 + 4);
        uint4 o;
        o.x = f2bf(a.x) | (f2bf(a.y) << 16);
        o.y = f2bf(a.z) | (f2bf(a.w) << 16);
        o.z = f2bf(b.x) | (f2bf(b.y) << 16);
        o.w = f2bf(b.z) | (f2bf(b.w) << 16);
        *reinterpret_cast<uint4*>(xblk + blk_idx(node, col0, IN_CH / 32)) = o;
        return;
    }
    int id = (blockIdx.x - XB) * 256 + threadIdx.x;   // 0..327679
    if (id < 65536) {                                  // W1: [128][256]
        int m = id >> 15;
        int r = id & 32767;
        int k = r >> 8, n = r & 255;
        const float* W = m ? W1n : W1r;
        u16* O = m ? o1n : o1r;
        O[n * 128 + k] = (u16)f2bf(W[r]);
    } else {                                           // W2/W3: [256][256]
        id -= 65536;
        int m = id >> 16;
        int r = id & 65535;
        int k = r >> 8, n = r & 255;
        const float* W = (m == 0) ? W2r : (m == 1) ? W2n : (m == 2) ? W3r : W3n;
        u16* O = (m == 0) ? o2r : (m == 1) ? o2n : (m == 2) ? o3r : o3n;
        O[n * 256 + k] = (u16)f2bf(W[r]);
    }
}

// ===========================================================================
// agg[i,:] = sum_{j in in(i)} feat[j,:]  — BLOCKED input, chunk-per-XCD.
// chunk = blockIdx & (NCH-1): with round-robin block->XCD dispatch, each XCD
// touches only its 64 B/row chunk -> 3.2 MB working set, L2-resident.
// agg written row-major (feeds GEMM A2).
// ===========================================================================
template<int D>
__global__ void __launch_bounds__(256)
gather_blk(const u16* __restrict__ feat, const int* __restrict__ row_start,
           const int* __restrict__ esrc, u16* __restrict__ agg)
{
    constexpr int NCH = D / 32;
    const int chunk = blockIdx.x & (NCH - 1);
    const int tile  = blockIdx.x / NCH;
    const int node  = tile * 64 + (threadIdx.x >> 2);
    const int lane  = threadIdx.x & 3;
    if (node >= N_NODES) return;
    const int s = row_start[node], e = row_start[node + 1];
    float acc[8] = {0.f, 0.f, 0.f, 0.f, 0.f, 0.f, 0.f, 0.f};
    const u16* fp = feat + (size_t)chunk * 64 + lane * 8;

    auto addr = [&](int sj) {
        return reinterpret_cast<const uint4*>(fp + ((size_t)(sj >> 1) * NCH) * 64 + (sj & 1) * 32);
    };
    auto add = [&](uint4 v) {
        acc[0] += bf2f(v.x & 0xFFFF); acc[1] += bf2f(v.x >> 16);
        acc[2] += bf2f(v.y & 0xFFFF); acc[3] += bf2f(v.y >> 16);
        acc[4] += bf2f(v.z & 0xFFFF); acc[5] += bf2f(v.z >> 16);
        acc[6] += bf2f(v.w & 0xFFFF); acc[7] += bf2f(v.w >> 16);
    };

    int j = s;
    for (; j + 3 < e; j += 4) {
        uint4 v0 = *addr(esrc[j]);
        uint4 v1 = *addr(esrc[j + 1]);
        uint4 v2 = *addr(esrc[j + 2]);
        uint4 v3 = *addr(esrc[j + 3]);
        add(v0); add(v1); add(v2); add(v3);
    }
    for (; j < e; ++j)
        add(*addr(esrc[j]));

    uint4 o;
    o.x = f2bf(acc[0]) | (f2bf(acc[1]) << 16);
    o.y = f2bf(acc[2]) | (f2bf(acc[3]) << 16);
    o.z = f2bf(acc[4]) | (f2bf(acc[5]) << 16);
    o.w = f2bf(acc[6]) | (f2bf(acc[7]) << 16);
    *reinterpret_cast<uint4*>(agg + (size_t)node * D + chunk * 32 + lane * 8) = o;
}

// ===========================================================================
// C[m,n] = act( A1@W1 + A2@W2 + bias ) — bf16 MFMA, full-width 128x256 tile.
// A1 read from BLOCKED layout; A2 (agg) row-major; output blocked (BLKOUT=1,
// feeds next layer's gather+A1) or row-major (final layer, feeds pool).
// ===========================================================================
template<int RELU, int K, int BLKOUT>
__global__ void __launch_bounds__(512)
mfma_gemm(const u16* __restrict__ A1, const u16* __restrict__ A2,
          const u16* __restrict__ B1t, const u16* __restrict__ B2t,
          const float* __restrict__ bias,
          u16* __restrict__ C,
          int M)
{
    __shared__ __align__(16) u16 As[128][40];
    __shared__ __align__(16) u16 Bs[256][40];

    // bijective XCD chunking (m204)
    const int orig = blockIdx.x;
    const int q = GEMM_WG / 8, r = GEMM_WG % 8;
    const int xcd = orig % 8;
    const int wg = (xcd < r ? xcd * (q + 1) : r * (q + 1) + (xcd - r) * q) + orig / 8;

    const int tid = threadIdx.x;
    const int bm = wg * 128;
    const int w  = tid >> 6;          // 0..7
    const int wm = (w >> 2) * 64;     // 0 or 64
    const int wn = (w & 3) * 64;      // 0,64,128,192
    const int l  = tid & 63;
    const int lr = l & 15;
    const int kb = (l >> 4) * 8;

    f32x4 acc[4][4];
    #pragma unroll
    for (int i = 0; i < 4; ++i)
        #pragma unroll
        for (int j = 0; j < 4; ++j)
            acc[i][j] = (f32x4){0.f, 0.f, 0.f, 0.f};

    const int row_s = tid >> 2;       // 0..127
    const int c8    = (tid & 3) * 8;

    for (int mat = 0; mat < 2; ++mat) {
        const u16* __restrict__ Ag = mat ? A2 : A1;
        const u16* __restrict__ Bg = mat ? B2t : B1t;
        for (int k0 = 0; k0 < K; k0 += 32) {
            // A tile: 128 rows x 32 k -> 512 uint4, 1 per thread
            {
                uint4 va = make_uint4(0u, 0u, 0u, 0u);
                int gr = bm + row_s;
                int col = k0 + c8;
                if (gr < M) {
                    if (mat == 0)   // blocked layout
                        va = *reinterpret_cast<const uint4*>(Ag + blk_idx(gr, col, K / 32));
                    else            // row-major agg
                        va = *reinterpret_cast<const uint4*>(Ag + (size_t)gr * K + col);
                }
                *reinterpret_cast<uint4*>(&As[row_s][c8]) = va;
            }
            // B tile: 256 rows x 32 k -> 1024 uint4, 2 per thread
            #pragma unroll
            for (int it = 0; it < 2; ++it) {
                int row = row_s + it * 128;
                uint4 vb = *reinterpret_cast<const uint4*>(Bg + (size_t)row * K + k0 + c8);
                *reinterpret_cast<uint4*>(&Bs[row][c8]) = vb;
            }
            __syncthreads();
            short8 af[4], bfr[4];
            #pragma unroll
            for (int f = 0; f < 4; ++f) {
                af[f]  = *reinterpret_cast<const short8*>(&As[wm + f * 16 + lr][kb]);
                bfr[f] = *reinterpret_cast<const short8*>(&Bs[wn + f * 16 + lr][kb]);
            }
            #pragma unroll
            for (int fm = 0; fm < 4; ++fm)
                #pragma unroll
                for (int fn = 0; fn < 4; ++fn)
                    acc[fm][fn] = __builtin_amdgcn_mfma_f32_16x16x32_bf16(
                        af[fm], bfr[fn], acc[fm][fn], 0, 0, 0);
            __syncthreads();
        }
    }

    const int r4 = (l >> 4) * 4;
    #pragma unroll
    for (int fm = 0; fm < 4; ++fm) {
        #pragma unroll
        for (int rr = 0; rr < 4; ++rr) {
            int row = bm + wm + fm * 16 + r4 + rr;
            if (row >= M) continue;
            #pragma unroll
            for (int fn = 0; fn < 4; ++fn) {
                int col = wn + fn * 16 + lr;
                float v = acc[fm][fn][rr] + bias[col];
                if (RELU) v = fmaxf(v, 0.f);
                if (BLKOUT)
                    C[blk_idx(row, col, HID / 32)] = (u16)f2bf(v);
                else
                    C[(size_t)row * HID + col] = (u16)f2bf(v);
            }
        }
    }
}

// ===========================================================================
// Pooling (batch sorted): inline binary search, two-stage mean + classifier
// ===========================================================================
__device__ __forceinline__ int lower_bound_g(const int* __restrict__ batch, int g)
{
    int lo = 0, hi = N_NODES;
    while (lo < hi) {
        int mid = (lo + hi) >> 1;
        if (batch[mid] < g) lo = mid + 1; else hi = mid;
    }
    return lo;
}

__global__ void pool1_kernel(const u16* __restrict__ h, const int* __restrict__ batch,
                             float* __restrict__ partial)
{
    int g = blockIdx.x >> 3;
    int c = blockIdx.x & 7;
    int t = threadIdx.x;      // 256
    int s = lower_bound_g(batch, g);
    int e = lower_bound_g(batch, g + 1);
    int cnt = e - s;
    int a = s + (int)(((long long)cnt * c) >> 3);
    int b = s + (int)(((long long)cnt * (c + 1)) >> 3);
    float acc = 0.f;
    for (int i = a; i < b; ++i)
        acc += bf2f(h[(size_t)i * HID + t]);
    partial[(size_t)blockIdx.x * HID + t] = acc;
}

__global__ void pool2_final(const float* __restrict__ partial, const int* __restrict__ batch,
                            const float* __restrict__ W_lin, const float* __restrict__ b_lin,
                            float* __restrict__ out)
{
    __shared__ float v[HID];
    int g = blockIdx.x;
    int t = threadIdx.x;
    float acc = 0.f;
    #pragma unroll
    for (int c = 0; c < 8; ++c)
        acc += partial[(size_t)(g * 8 + c) * HID + t];
    float cnt = fmaxf((float)(lower_bound_g(batch, g + 1) - lower_bound_g(batch, g)), 1.f);
    v[t] = acc / cnt;
    __syncthreads();
    if (t < N_CLASSES) {
        float s = b_lin[t];
        for (int k = 0; k < HID; ++k)
            s += v[k] * W_lin[k * N_CLASSES + t];
        out[g * N_CLASSES + t] = s;
    }
}

// ===========================================================================
extern "C" void kernel_launch(void* const* d_in, const int* in_sizes, int n_in,
                              void* d_out, int out_size, void* d_ws, size_t ws_size,
                              hipStream_t stream)
{
    const float* x     = (const float*)d_in[0];
    const int*   ei    = (const int*)d_in[1];
    const int*   batch = (const int*)d_in[2];
    const float* W1r = (const float*)d_in[3];
    const float* W1n = (const float*)d_in[4];
    const float* b1  = (const float*)d_in[5];
    const float* W2r = (const float*)d_in[6];
    const float* W2n = (const float*)d_in[7];
    const float* b2  = (const float*)d_in[8];
    const float* W3r = (const float*)d_in[9];
    const float* W3n = (const float*)d_in[10];
    const float* b3  = (const float*)d_in[11];
    const float* Wl  = (const float*)d_in[12];
    const float* bl  = (const float*)d_in[13];
    float* out = (float*)d_out;

    const int* src = ei;
    const int* dst = ei + N_EDGES;

    char* base = (char*)d_ws;
    size_t off = 0;
    auto alloc = [&](size_t bytes) { char* p = base + off; off += (bytes + 255) & ~(size_t)255; return p; };
    u16* x_blk = (u16*)alloc((size_t)N_NODES * IN_CH * 2);   // blocked
    u16* h1b   = (u16*)alloc((size_t)N_NODES * HID * 2);     // blocked; reused row-major for layer-3 out
    u16* h2b   = (u16*)alloc((size_t)N_NODES * HID * 2);     // blocked
    u16* agg   = (u16*)alloc((size_t)N_NODES * HID * 2);     // row-major
    u16* wt1r = (u16*)alloc((size_t)HID * IN_CH * 2);
    u16* wt1n = (u16*)alloc((size_t)HID * IN_CH * 2);
    u16* wt2r = (u16*)alloc((size_t)HID * HID * 2);
    u16* wt2n = (u16*)alloc((size_t)HID * HID * 2);
    u16* wt3r = (u16*)alloc((size_t)HID * HID * 2);
    u16* wt3n = (u16*)alloc((size_t)HID * HID * 2);
    float* partial = (float*)alloc((size_t)N_GRAPHS * 8 * HID * 4);
    int* row_start = (int*)alloc((size_t)(N_NODES + 1) * 4);
    int* esrc      = (int*)alloc((size_t)N_EDGES * 4);
    uint32_t* tmp  = (uint32_t*)alloc((size_t)NB * CAP * 4);
    int* gcnt      = (int*)alloc((size_t)NB * 4);
    int* boff      = (int*)alloc((size_t)NB * 4);

    u16* h3 = h1b;   // layer-3 row-major output aliases h1b (dead by then)

    // ---- CSR build (4 dispatches: memset + bin + scan + debin) ----
    hipMemsetAsync(gcnt, 0, NB * sizeof(int), stream);
    bin_pass<<<(N_EDGES + EPB - 1) / EPB, 512, 0, stream>>>(src, dst, gcnt, tmp);
    bucket_scan<<<1, 512, 0, stream>>>(gcnt, boff, row_start);
    debin2<<<NB, 256, 0, stream>>>(tmp, gcnt, boff, row_start, esrc);

    // ---- conversions (1 dispatch) ----
    cvt_all<<<XB + 1280, 256, 0, stream>>>(x, x_blk, W1r, W1n, W2r, W2n, W3r, W3n,
                                           wt1r, wt1n, wt2r, wt2n, wt3r, wt3n);

    // ---- layer 1 (K=128, relu) ----
    gather_blk<IN_CH><<<GTILES * (IN_CH / 32), 256, 0, stream>>>(x_blk, row_start, esrc, agg);
    mfma_gemm<1, IN_CH, 1><<<GEMM_WG, 512, 0, stream>>>(x_blk, agg, wt1r, wt1n, b1, h1b, N_NODES);

    // ---- layer 2 (K=256, relu) ----
    gather_blk<HID><<<GTILES * (HID / 32), 256, 0, stream>>>(h1b, row_start, esrc, agg);
    mfma_gemm<1, HID, 1><<<GEMM_WG, 512, 0, stream>>>(h1b, agg, wt2r, wt2n, b2, h2b, N_NODES);

    // ---- layer 3 (K=256, no relu, row-major out for pool) ----
    gather_blk<HID><<<GTILES * (HID / 32), 256, 0, stream>>>(h2b, row_start, esrc, agg);
    mfma_gemm<0, HID, 0><<<GEMM_WG, 512, 0, stream>>>(h2b, agg, wt3r, wt3n, b3, h3, N_NODES);

    // ---- pool + classifier (2 dispatches) ----
    pool1_kernel<<<N_GRAPHS * 8, HID, 0, stream>>>(h3, batch, partial);
    pool2_final<<<N_GRAPHS, HID, 0, stream>>>(partial, batch, Wl, bl, out);
}

// Round 13
// 329.122 us; speedup vs baseline: 1.0451x; 1.0451x over previous
//
#include <hip/hip_runtime.h>
#include <stdint.h>

#define N_NODES 50000
#define N_EDGES 800000
#define IN_CH 128
#define HID 256
#define N_GRAPHS 64
#define N_CLASSES 10

#define FUSED_WG ((N_NODES + 63) / 64)        // 782 blocks (64-row tiles)
#define NB ((N_NODES + 127) / 128)            // 391 dst buckets (128 nodes each)
#define EPB 4096                              // edges per bin_pass block
#define CAP 4096                              // slots per bucket (mean 2048, 45 sigma)

typedef unsigned short u16;
typedef __attribute__((ext_vector_type(8))) short short8;
typedef __attribute__((ext_vector_type(4))) float f32x4;

__device__ __forceinline__ float bf2f(uint32_t u) {
    union { uint32_t i; float f; } v; v.i = u << 16; return v.f;
}
__device__ __forceinline__ uint32_t f2bf(float f) {
    union { float f; uint32_t i; } v; v.f = f;
    return (v.i + 0x7FFFu + ((v.i >> 16) & 1u)) >> 16;   // RNE
}

// ===========================================================================
// CSR build: bin (fixed-capacity buckets) -> bucket scan -> debin
// ===========================================================================
__global__ void __launch_bounds__(512) bin_pass(const int* __restrict__ src,
                                                const int* __restrict__ dst,
                                                int* __restrict__ gcnt,
                                                uint32_t* __restrict__ tmp)
{
    __shared__ int hist[NB];
    __shared__ int base[NB];
    int t = threadIdx.x;
    for (int i = t; i < NB; i += 512) hist[i] = 0;
    __syncthreads();
    const int e0 = blockIdx.x * EPB;
    int b_[8], s_[8], d_[8];
    #pragma unroll
    for (int k = 0; k < 8; ++k) {
        int e = e0 + k * 512 + t;
        if (e < N_EDGES) {
            int d = dst[e];
            b_[k] = d >> 7;
            d_[k] = d & 127;
            s_[k] = src[e];
            atomicAdd(&hist[b_[k]], 1);
        } else b_[k] = -1;
    }
    __syncthreads();
    for (int i = t; i < NB; i += 512) {
        int c = hist[i];
        base[i] = c ? atomicAdd(&gcnt[i], c) : 0;
        hist[i] = 0;
    }
    __syncthreads();
    #pragma unroll
    for (int k = 0; k < 8; ++k) {
        if (b_[k] >= 0) {
            int r = atomicAdd(&hist[b_[k]], 1);
            int pos = base[b_[k]] + r;
            if (pos < CAP)
                tmp[(size_t)b_[k] * CAP + pos] = ((uint32_t)s_[k] << 7) | (uint32_t)d_[k];
        }
    }
}

__global__ void __launch_bounds__(512) bucket_scan(const int* __restrict__ gcnt,
                                                   int* __restrict__ boff,
                                                   int* __restrict__ row_start)
{
    __shared__ int buf[512];
    int t = threadIdx.x;
    int v = (t < NB) ? gcnt[t] : 0;
    buf[t] = v;
    __syncthreads();
    #pragma unroll
    for (int off = 1; off < 512; off <<= 1) {
        int a = (t >= off) ? buf[t - off] : 0;
        __syncthreads();
        buf[t] += a;
        __syncthreads();
    }
    if (t < NB) boff[t] = buf[t] - v;
    if (t == 0) row_start[N_NODES] = N_EDGES;
}

__global__ void __launch_bounds__(256) debin2(const uint32_t* __restrict__ tmp,
                                              const int* __restrict__ gcnt,
                                              const int* __restrict__ boff,
                                              int* __restrict__ row_start,
                                              int* __restrict__ esrc)
{
    __shared__ int h[128];
    __shared__ int pre[128];
    __shared__ int cur[128];
    const int b = blockIdx.x;
    const int n0 = b * 128;
    const int nn = min(128, N_NODES - n0);
    const int t = threadIdx.x;
    const int cnt = min(gcnt[b], CAP);
    const int bb = boff[b];
    const uint32_t* te = tmp + (size_t)b * CAP;

    if (t < 128) h[t] = 0;
    __syncthreads();
    for (int p = t; p < cnt; p += 256)
        atomicAdd(&h[te[p] & 127u], 1);
    __syncthreads();
    if (t < 128) pre[t] = h[t];
    __syncthreads();
    #pragma unroll
    for (int off = 1; off < 128; off <<= 1) {
        int a = (t >= off && t < 128) ? pre[t - off] : 0;
        __syncthreads();
        if (t < 128) pre[t] += a;
        __syncthreads();
    }
    if (t < nn) {
        int rs = bb + pre[t] - h[t];   // exclusive
        row_start[n0 + t] = rs;
        cur[t] = rs;
    }
    __syncthreads();
    for (int p = t; p < cnt; p += 256) {
        uint32_t v = te[p];
        int pos = atomicAdd(&cur[v & 127u], 1);
        esrc[pos] = (int)(v >> 7);
    }
}

// ===========================================================================
// fused conversions: x -> bf16 row-major (vectorized) + 6 weight transposes
// ===========================================================================
#define XB 3125   // N_NODES*IN_CH/8/256
__global__ void __launch_bounds__(256)
cvt_all(const float* __restrict__ x, u16* __restrict__ xb,
        const float* __restrict__ W1r, const float* __restrict__ W1n,
        const float* __restrict__ W2r, const float* __restrict__ W2n,
        const float* __restrict__ W3r, const float* __restrict__ W3n,
        u16* __restrict__ o1r, u16* __restrict__ o1n,
        u16* __restrict__ o2r, u16* __restrict__ o2n,
        u16* __restrict__ o3r, u16* __restrict__ o3n)
{
    if (blockIdx.x < XB) {
        int id = blockIdx.x * 256 + threadIdx.x;
        const float4 a = *reinterpret_cast<const float4*>(x + (size_t)id * 8);
        const float4 b = *reinterpret_cast<const float4*>(x + (size_t)id * 8 + 4);
        uint4 o;
        o.x = f2bf(a.x) | (f2bf(a.y) << 16);
        o.y = f2bf(a.z) | (f2bf(a.w) << 16);
        o.z = f2bf(b.x) | (f2bf(b.y) << 16);
        o.w = f2bf(b.z) | (f2bf(b.w) << 16);
        *reinterpret_cast<uint4*>(xb + (size_t)id * 8) = o;
        return;
    }
    int id = (blockIdx.x - XB) * 256 + threadIdx.x;   // 0..327679
    if (id < 65536) {                                  // W1: [128][256]
        int m = id >> 15;
        int r = id & 32767;
        int k = r >> 8, n = r & 255;
        const float* W = m ? W1n : W1r;
        u16* O = m ? o1n : o1r;
        O[n * 128 + k] = (u16)f2bf(W[r]);
    } else {                                           // W2/W3: [256][256]
        id -= 65536;
        int m = id >> 16;
        int r = id & 65535;
        int k = r >> 8, n = r & 255;
        const float* W = (m == 0) ? W2r : (m == 1) ? W2n : (m == 2) ? W3r : W3n;
        u16* O = (m == 0) ? o2r : (m == 1) ? o2n : (m == 2) ? o3r : o3n;
        O[n * 256 + k] = (u16)f2bf(W[r]);
    }
}

// ===========================================================================
// FUSED GraphConv layer: per 64-row tile,
//   phase A: agg[r,:] = sum_{j in in(r)} feat[j,:]  -> LDS (never to global)
//   phase B: C[r,:] = act( feat[r,:]@B1t^T + agg[r,:]@B2t^T + bias )
// 512 threads (8 waves). Gather uses R11's access pattern (LPN lanes x 16 B,
// contiguous 128/256 B per node per instr) with column-half phasing (R10).
// agg LDS stride K+8 halves -> 2-way bank alias on ds_read_b128 (free, m136).
// ===========================================================================
template<int RELU, int K>
__global__ void __launch_bounds__(512, 4)
fused_layer(const u16* __restrict__ feat,
            const int* __restrict__ row_start,
            const int* __restrict__ esrc,
            const u16* __restrict__ B1t,      // [256][K] bf16
            const u16* __restrict__ B2t,      // [256][K] bf16
            const float* __restrict__ bias,
            u16* __restrict__ C,              // [N][256] bf16
            int M)
{
    __shared__ __align__(16) u16 agg[64][K + 8];
    __shared__ __align__(16) u16 As[64][40];
    __shared__ __align__(16) u16 Bs[256][40];

    // bijective XCD chunking (m204)
    const int orig = blockIdx.x;
    const int q = FUSED_WG / 8, r = FUSED_WG % 8;
    const int xcd = orig % 8;
    const int wg = (xcd < r ? xcd * (q + 1) : r * (q + 1) + (xcd - r) * q) + orig / 8;

    const int tid = threadIdx.x;
    const int bm = wg * 64;

    // ---------------- phase A: gather into LDS ----------------
    {
        constexpr int NCH = K / 2;          // cols per half (128 or 64)
        constexpr int LPN = NCH / 8;        // lanes per node (16 or 8)
        constexpr int NPP = 512 / LPN;      // nodes per pass (32 or 64)
        constexpr int PASSES = 64 / NPP;    // passes per half (2 or 1)
        const int lane = tid % LPN;
        const int nl0  = tid / LPN;

        for (int h = 0; h < 2; ++h) {
            const u16* fp = feat + h * NCH + lane * 8;
            #pragma unroll
            for (int p = 0; p < PASSES; ++p) {
                const int nl = p * NPP + nl0;
                const int node = bm + nl;
                float acc[8] = {0.f, 0.f, 0.f, 0.f, 0.f, 0.f, 0.f, 0.f};
                if (node < M) {
                    const int s = row_start[node], e = row_start[node + 1];
                    auto add = [&](uint4 v) {
                        acc[0] += bf2f(v.x & 0xFFFF); acc[1] += bf2f(v.x >> 16);
                        acc[2] += bf2f(v.y & 0xFFFF); acc[3] += bf2f(v.y >> 16);
                        acc[4] += bf2f(v.z & 0xFFFF); acc[5] += bf2f(v.z >> 16);
                        acc[6] += bf2f(v.w & 0xFFFF); acc[7] += bf2f(v.w >> 16);
                    };
                    int j = s;
                    for (; j + 3 < e; j += 4) {
                        int s0 = esrc[j], s1 = esrc[j + 1], s2 = esrc[j + 2], s3 = esrc[j + 3];
                        uint4 v0 = *reinterpret_cast<const uint4*>(fp + (size_t)s0 * K);
                        uint4 v1 = *reinterpret_cast<const uint4*>(fp + (size_t)s1 * K);
                        uint4 v2 = *reinterpret_cast<const uint4*>(fp + (size_t)s2 * K);
                        uint4 v3 = *reinterpret_cast<const uint4*>(fp + (size_t)s3 * K);
                        add(v0); add(v1); add(v2); add(v3);
                    }
                    for (; j < e; ++j)
                        add(*reinterpret_cast<const uint4*>(fp + (size_t)esrc[j] * K));
                }
                uint4 o;
                o.x = f2bf(acc[0]) | (f2bf(acc[1]) << 16);
                o.y = f2bf(acc[2]) | (f2bf(acc[3]) << 16);
                o.z = f2bf(acc[4]) | (f2bf(acc[5]) << 16);
                o.w = f2bf(acc[6]) | (f2bf(acc[7]) << 16);
                *reinterpret_cast<uint4*>(&agg[nl][h * NCH + lane * 8]) = o;
            }
        }
    }
    __syncthreads();

    // ---------------- phase B: MFMA GEMM ----------------
    const int w  = tid >> 6;          // 0..7
    const int wm = (w >> 2) * 32;     // 0 or 32
    const int wn = (w & 3) * 64;      // 0,64,128,192
    const int l  = tid & 63;
    const int lr = l & 15;
    const int kb = (l >> 4) * 8;

    f32x4 acc[2][4];
    #pragma unroll
    for (int i = 0; i < 2; ++i)
        #pragma unroll
        for (int j = 0; j < 4; ++j)
            acc[i][j] = (f32x4){0.f, 0.f, 0.f, 0.f};

    const int row_a = tid >> 2;       // 0..127 (A uses <256 threads: rows 0..63)
    const int c8    = (tid & 3) * 8;

    // mat 0: A1 = feat rows (global, staged); B1t
    for (int k0 = 0; k0 < K; k0 += 32) {
        if (tid < 256) {
            uint4 va = make_uint4(0u, 0u, 0u, 0u);
            int gr = bm + row_a;
            if (gr < M)
                va = *reinterpret_cast<const uint4*>(feat + (size_t)gr * K + k0 + c8);
            *reinterpret_cast<uint4*>(&As[row_a][c8]) = va;
        }
        #pragma unroll
        for (int it = 0; it < 2; ++it) {
            int row = (tid >> 2) + it * 128;
            uint4 vb = *reinterpret_cast<const uint4*>(B1t + (size_t)row * K + k0 + c8);
            *reinterpret_cast<uint4*>(&Bs[row][c8]) = vb;
        }
        __syncthreads();
        short8 af[2], bfr[4];
        #pragma unroll
        for (int f = 0; f < 2; ++f)
            af[f] = *reinterpret_cast<const short8*>(&As[wm + f * 16 + lr][kb]);
        #pragma unroll
        for (int f = 0; f < 4; ++f)
            bfr[f] = *reinterpret_cast<const short8*>(&Bs[wn + f * 16 + lr][kb]);
        #pragma unroll
        for (int fm = 0; fm < 2; ++fm)
            #pragma unroll
            for (int fn = 0; fn < 4; ++fn)
                acc[fm][fn] = __builtin_amdgcn_mfma_f32_16x16x32_bf16(
                    af[fm], bfr[fn], acc[fm][fn], 0, 0, 0);
        __syncthreads();
    }

    // mat 1: A2 = agg (LDS-resident, no staging); B2t
    for (int k0 = 0; k0 < K; k0 += 32) {
        #pragma unroll
        for (int it = 0; it < 2; ++it) {
            int row = (tid >> 2) + it * 128;
            uint4 vb = *reinterpret_cast<const uint4*>(B2t + (size_t)row * K + k0 + c8);
            *reinterpret_cast<uint4*>(&Bs[row][c8]) = vb;
        }
        __syncthreads();
        short8 af[2], bfr[4];
        #pragma unroll
        for (int f = 0; f < 2; ++f)
            af[f] = *reinterpret_cast<const short8*>(&agg[wm + f * 16 + lr][k0 + kb]);
        #pragma unroll
        for (int f = 0; f < 4; ++f)
            bfr[f] = *reinterpret_cast<const short8*>(&Bs[wn + f * 16 + lr][kb]);
        #pragma unroll
        for (int fm = 0; fm < 2; ++fm)
            #pragma unroll
            for (int fn = 0; fn < 4; ++fn)
                acc[fm][fn] = __builtin_amdgcn_mfma_f32_16x16x32_bf16(
                    af[fm], bfr[fn], acc[fm][fn], 0, 0, 0);
        __syncthreads();
    }

    // epilogue
    const int r4 = (l >> 4) * 4;
    #pragma unroll
    for (int fm = 0; fm < 2; ++fm) {
        #pragma unroll
        for (int rr = 0; rr < 4; ++rr) {
            int row = bm + wm + fm * 16 + r4 + rr;
            if (row >= M) continue;
            #pragma unroll
            for (int fn = 0; fn < 4; ++fn) {
                int col = wn + fn * 16 + lr;
                float v = acc[fm][fn][rr] + bias[col];
                if (RELU) v = fmaxf(v, 0.f);
                C[(size_t)row * HID + col] = (u16)f2bf(v);
            }
        }
    }
}

// ===========================================================================
// Pooling (batch sorted): inline binary search, two-stage mean + classifier
// ===========================================================================
__device__ __forceinline__ int lower_bound_g(const int* __restrict__ batch, int g)
{
    int lo = 0, hi = N_NODES;
    while (lo < hi) {
        int mid = (lo + hi) >> 1;
        if (batch[mid] < g) lo = mid + 1; else hi = mid;
    }
    return lo;
}

__global__ void pool1_kernel(const u16* __restrict__ h, const int* __restrict__ batch,
                             float* __restrict__ partial)
{
    int g = blockIdx.x >> 3;
    int c = blockIdx.x & 7;
    int t = threadIdx.x;      // 256
    int s = lower_bound_g(batch, g);
    int e = lower_bound_g(batch, g + 1);
    int cnt = e - s;
    int a = s + (int)(((long long)cnt * c) >> 3);
    int b = s + (int)(((long long)cnt * (c + 1)) >> 3);
    float acc = 0.f;
    for (int i = a; i < b; ++i)
        acc += bf2f(h[(size_t)i * HID + t]);
    partial[(size_t)blockIdx.x * HID + t] = acc;
}

__global__ void pool2_final(const float* __restrict__ partial, const int* __restrict__ batch,
                            const float* __restrict__ W_lin, const float* __restrict__ b_lin,
                            float* __restrict__ out)
{
    __shared__ float v[HID];
    int g = blockIdx.x;
    int t = threadIdx.x;
    float acc = 0.f;
    #pragma unroll
    for (int c = 0; c < 8; ++c)
        acc += partial[(size_t)(g * 8 + c) * HID + t];
    float cnt = fmaxf((float)(lower_bound_g(batch, g + 1) - lower_bound_g(batch, g)), 1.f);
    v[t] = acc / cnt;
    __syncthreads();
    if (t < N_CLASSES) {
        float s = b_lin[t];
        for (int k = 0; k < HID; ++k)
            s += v[k] * W_lin[k * N_CLASSES + t];
        out[g * N_CLASSES + t] = s;
    }
}

// ===========================================================================
extern "C" void kernel_launch(void* const* d_in, const int* in_sizes, int n_in,
                              void* d_out, int out_size, void* d_ws, size_t ws_size,
                              hipStream_t stream)
{
    const float* x     = (const float*)d_in[0];
    const int*   ei    = (const int*)d_in[1];
    const int*   batch = (const int*)d_in[2];
    const float* W1r = (const float*)d_in[3];
    const float* W1n = (const float*)d_in[4];
    const float* b1  = (const float*)d_in[5];
    const float* W2r = (const float*)d_in[6];
    const float* W2n = (const float*)d_in[7];
    const float* b2  = (const float*)d_in[8];
    const float* W3r = (const float*)d_in[9];
    const float* W3n = (const float*)d_in[10];
    const float* b3  = (const float*)d_in[11];
    const float* Wl  = (const float*)d_in[12];
    const float* bl  = (const float*)d_in[13];
    float* out = (float*)d_out;

    const int* src = ei;
    const int* dst = ei + N_EDGES;

    char* base = (char*)d_ws;
    size_t off = 0;
    auto alloc = [&](size_t bytes) { char* p = base + off; off += (bytes + 255) & ~(size_t)255; return p; };
    u16* x_bf = (u16*)alloc((size_t)N_NODES * IN_CH * 2);
    u16* hA   = (u16*)alloc((size_t)N_NODES * HID * 2);
    u16* hB   = (u16*)alloc((size_t)N_NODES * HID * 2);
    u16* wt1r = (u16*)alloc((size_t)HID * IN_CH * 2);
    u16* wt1n = (u16*)alloc((size_t)HID * IN_CH * 2);
    u16* wt2r = (u16*)alloc((size_t)HID * HID * 2);
    u16* wt2n = (u16*)alloc((size_t)HID * HID * 2);
    u16* wt3r = (u16*)alloc((size_t)HID * HID * 2);
    u16* wt3n = (u16*)alloc((size_t)HID * HID * 2);
    float* partial = (float*)alloc((size_t)N_GRAPHS * 8 * HID * 4);
    int* row_start = (int*)alloc((size_t)(N_NODES + 1) * 4);
    int* esrc      = (int*)alloc((size_t)N_EDGES * 4);
    uint32_t* tmp  = (uint32_t*)alloc((size_t)NB * CAP * 4);
    int* gcnt      = (int*)alloc((size_t)NB * 4);
    int* boff      = (int*)alloc((size_t)NB * 4);

    // ---- CSR build (4 dispatches: memset + bin + scan + debin) ----
    hipMemsetAsync(gcnt, 0, NB * sizeof(int), stream);
    bin_pass<<<(N_EDGES + EPB - 1) / EPB, 512, 0, stream>>>(src, dst, gcnt, tmp);
    bucket_scan<<<1, 512, 0, stream>>>(gcnt, boff, row_start);
    debin2<<<NB, 256, 0, stream>>>(tmp, gcnt, boff, row_start, esrc);

    // ---- conversions (1 dispatch) ----
    cvt_all<<<XB + 1280, 256, 0, stream>>>(x, x_bf, W1r, W1n, W2r, W2n, W3r, W3n,
                                           wt1r, wt1n, wt2r, wt2n, wt3r, wt3n);

    // ---- fused layers (3 dispatches) ----
    fused_layer<1, IN_CH><<<FUSED_WG, 512, 0, stream>>>(x_bf, row_start, esrc,
                                                        wt1r, wt1n, b1, hA, N_NODES);
    fused_layer<1, HID><<<FUSED_WG, 512, 0, stream>>>(hA, row_start, esrc,
                                                      wt2r, wt2n, b2, hB, N_NODES);
    fused_layer<0, HID><<<FUSED_WG, 512, 0, stream>>>(hB, row_start, esrc,
                                                      wt3r, wt3n, b3, hA, N_NODES);

    // ---- pool + classifier (2 dispatches) ----
    pool1_kernel<<<N_GRAPHS * 8, HID, 0, stream>>>(hA, batch, partial);
    pool2_final<<<N_GRAPHS, HID, 0, stream>>>(partial, batch, Wl, bl, out);
}